// Round 13
// baseline (154.588 us; speedup 1.0000x reference)
//
#include <hip/hip_runtime.h>

// retinex_synthesis, SINGLE-kernel rolling separable blur.
// out = clip(exp2(blur(log2(1+bg) - log2(1+ins)) + log2(1+ins)) - 1, 0, 1)
//
// R17 = R11 base (best: 56us disp) + il2 LDS ring: the epilogue's
// log2(1+ins) is already computed during staging (operand of the staged
// difference) -- keep it, write center-64 cols to a 3rd ring, and emit
// reads it from LDS instead of re-loading ins from L2 (-8 global loads,
// -8 addr calcs, -8 mul/add per thread-chunk, -50MB L2 traffic).
// R16 post-mortem: emit LDS-read halving = NULL (5th structural null).
//
// Schedule (il2-write moved to phase 2 to avoid a mod-64 ring race):
//   iter k=0..8: P1: stage-d(k) (pb,pn -> sd; pn stays LIVE);
//   barA; P2: il2-write(k) (from pn) -> prefetch(k+1) (overwrites pn)
//   -> h-blur(k); barB; P3: emit(k-1) [k>=1].
// il2 hazard audit (64 slots): emit(k-1) reads rows [32k-32, 32k-1] in
// interval B(k)..A(k+1); RAW rows [32k-15,32k-1] from il2w(k) ordered by
// barB(k), rows [32k-32,32k-16] from il2w(k-1) two barriers back; WAR vs
// il2w(k+1) (slot-aliases [32k-47,32k-16]) separated by barA(k+1). SAFE.
// hr ring hazards unchanged from R11 (proven). Prefetch consumed next
// iter P1: ~3/4 iteration of latency budget across barB.
//
// Geometry (proven): 64w x 256t strips, grid 8*2*48 = 768 = 3 blocks/CU.
// LDS = sd 12,800 + hr 17,408 + il2 17,408 = 47,616 B -> 3 blocks/CU.
// Packed blur FMAs (R11): v_pk_fma_f32, zero-padded compile-time coeff
// pairs, per-output accumulation order preserved. log2 domain (R11).
// Barriers LDS-only (R9-proven). Emit addressing wave-uniform -> SALU.

constexpr int W_ = 512, H_ = 512, NIMG = 48;
constexpr int SPITCH = 100;  // staging pitch: 96 cols + 4 (R11-proven)
constexpr int RPITCH = 68;   // ring pitch: 64 cols + 4

typedef float v2f __attribute__((ext_vector_type(2)));

// LDS-only barrier: cross-wave LDS visibility needs lgkmcnt(0) commit, but
// NOT vmcnt drain; prefetch loads stay in flight across barriers.
#define LDS_BARRIER()                                      \
  do {                                                     \
    asm volatile("" ::: "memory");                         \
    asm volatile("s_waitcnt lgkmcnt(0)" ::: "memory");     \
    __builtin_amdgcn_s_barrier();                          \
    asm volatile("" ::: "memory");                         \
  } while (0)

__device__ constexpr float G[31] = {
    8.8805851e-04f, 1.5861066e-03f, 2.7217699e-03f, 4.4874399e-03f,
    7.1084368e-03f, 1.0818767e-02f, 1.5820117e-02f, 2.2226435e-02f,
    3.0002549e-02f, 3.8911209e-02f, 4.8486352e-02f, 5.8048702e-02f,
    6.6771901e-02f, 7.3794364e-02f, 7.8357552e-02f, 7.9940480e-02f,
    7.8357552e-02f, 7.3794364e-02f, 6.6771901e-02f, 5.8048702e-02f,
    4.8486352e-02f, 3.8911209e-02f, 3.0002549e-02f, 2.2226435e-02f,
    1.5820117e-02f, 1.0818767e-02f, 7.1084368e-03f, 4.4874399e-03f,
    2.7217699e-03f, 1.5861066e-03f, 8.8805851e-04f};

// Zero-padded coefficient: compile-time c -> literal (0 outside [0,31)).
__device__ constexpr float gc(int c) { return (c >= 0 && c < 31) ? G[c] : 0.f; }

__global__ __launch_bounds__(256, 3) void retinex_roll(const float* __restrict__ bg,
                                                       const float* __restrict__ ins,
                                                       float* __restrict__ out) {
  __shared__ __align__(16) float sd[32 * SPITCH];   // 12,800 B: staged d chunk
  __shared__ __align__(16) float hr[64 * RPITCH];   // 17,408 B: h-blurred ring
  __shared__ __align__(16) float il2[64 * RPITCH];  // 17,408 B: log2(1+ins) ring

  const int tid  = threadIdx.x;
  const int lane = tid & 63;
  const int x0 = blockIdx.x * 64;
  const int y0 = blockIdx.y * 256;
  const size_t base = (size_t)blockIdx.z * (size_t)(H_ * W_);

  // Staging geometry (k-invariant): 768 float4 items = 32 rows x 24 slots.
  int sr[3], sc[3], gx[3]; bool okx[3];
#pragma unroll
  for (int s = 0; s < 3; ++s) {
    const int item = tid + 256 * s;
    sr[s] = item / 24;
    sc[s] = item - 24 * sr[s];
    gx[s] = x0 - 16 + 4 * sc[s];          // float4-aligned; OOB is whole-float4
    okx[s] = (unsigned)gx[s] < (unsigned)W_;
  }
  const int hrow = tid >> 3;              // h-blur: staged row 0..31
  const int hcg  = tid & 7;               // h-blur: col group (8 cols each)
  // emit row-group 0..3 — wave-uniform: force scalar so ring addressing is SALU
  const int eg = __builtin_amdgcn_readfirstlane(tid >> 6);

  // Initial prefetch: chunk 0 = rows y0-15 .. y0+16.
  float4 pb[3], pn[3];
#pragma unroll
  for (int s = 0; s < 3; ++s) {
    const int gy = y0 - 15 + sr[s];
    pb[s] = make_float4(0.f, 0.f, 0.f, 0.f);
    pn[s] = pb[s];
    if (okx[s] && (unsigned)gy < (unsigned)H_) {
      const size_t a = base + (size_t)gy * W_ + gx[s];
      pb[s] = *(const float4*)(bg + a);
      pn[s] = *(const float4*)(ins + a);
    }
  }

#pragma unroll 1
  for (int k = 0; k < 9; ++k) {
    // ---- P1: stage d(k) = log2(1+bg)-log2(1+ins). pn stays live for P2.
    float4 nl[3];   // log2(1+ins) per staged item (kept for il2 ring)
#pragma unroll
    for (int s = 0; s < 3; ++s) {
      nl[s].x = __builtin_amdgcn_logf(1.f + pn[s].x);
      nl[s].y = __builtin_amdgcn_logf(1.f + pn[s].y);
      nl[s].z = __builtin_amdgcn_logf(1.f + pn[s].z);
      nl[s].w = __builtin_amdgcn_logf(1.f + pn[s].w);
      float4 v;
      v.x = __builtin_amdgcn_logf(1.f + pb[s].x) - nl[s].x;
      v.y = __builtin_amdgcn_logf(1.f + pb[s].y) - nl[s].y;
      v.z = __builtin_amdgcn_logf(1.f + pb[s].z) - nl[s].z;
      v.w = __builtin_amdgcn_logf(1.f + pb[s].w) - nl[s].w;
      *(float4*)(sd + sr[s] * SPITCH + 4 * sc[s]) = v;   // slot%8=(sr+sc)%8
    }
    LDS_BARRIER();   // A: sd ready; orders prev emit's ring reads vs P2 writes

    // ---- P2a: il2-write(k): center 64 cols of staged rows -> il2 ring.
    //      (rows 32k-15+sr, slot mod 64; cols 4sc-16 for sc in [4,20))
#pragma unroll
    for (int s = 0; s < 3; ++s) {
      if (sc[s] >= 4 && sc[s] < 20) {
        const int r64 = (32 * k + 113 + sr[s]) & 63;   // (32k-15+sr) mod 64
        *(float4*)(il2 + r64 * RPITCH + 4 * sc[s] - 16) = nl[s];
      }
    }
    // ---- P2b: prefetch chunk k+1 (overwrites pb/pn AFTER il2 write;
    //      consumed next iter P1 -> ~3/4 iteration in flight).
    if (k < 8) {
#pragma unroll
      for (int s = 0; s < 3; ++s) {
        const int gy = y0 + 32 * (k + 1) - 15 + sr[s];
        float4 b0 = make_float4(0.f, 0.f, 0.f, 0.f), n0 = b0;
        if (okx[s] && (unsigned)gy < (unsigned)H_) {
          const size_t a = base + (size_t)gy * W_ + gx[s];
          b0 = *(const float4*)(bg + a);
          n0 = *(const float4*)(ins + a);
        }
        pb[s] = b0; pn[s] = n0;
      }
    }
    // ---- P2c: h-blur staged row `hrow`, cols 8*hcg..+7 -> hr ring (packed).
    {
      v2f o2[4];
#pragma unroll
      for (int m = 0; m < 4; ++m) o2[m] = (v2f){0.f, 0.f};
      const float4* p4 = (const float4*)(sd + hrow * SPITCH) + 2 * hcg;
#pragma unroll
      for (int q = 0; q < 10; ++q) {       // slot%8=(hrow+2hcg+q)%8: balanced
        const float4 v = p4[q];
        const float w4[4] = {v.x, v.y, v.z, v.w};
#pragma unroll
        for (int t = 0; t < 4; ++t) {
          const int pos = 4 * q + t;       // window index: sd col 8*hcg + pos
          const v2f vv = {w4[t], w4[t]};
#pragma unroll
          for (int m = 0; m < 4; ++m) {
            const int c0 = pos - 1 - 2 * m;   // compile-time
            if (c0 >= 0 && c0 < 32) {
              const v2f kc = {gc(c0), gc(c0 - 1)};
              o2[m] = __builtin_elementwise_fma(vv, kc, o2[m]);
            }
          }
        }
      }
      const int slot = (32 * k - 15 + hrow + 128) & 63;  // logical row mod 64
      float* dst = hr + slot * RPITCH + 8 * hcg;
      *(float4*)(dst)     = make_float4(o2[0].x, o2[0].y, o2[1].x, o2[1].y);
      *(float4*)(dst + 4) = make_float4(o2[2].x, o2[2].y, o2[3].x, o2[3].y);
    }
    LDS_BARRIER();   // B: hr rows + il2 rows for this chunk committed

    // ---- P3: emit rows [32(k-1), 32k): v-blur from hr + il2 epilogue.
    if (k >= 1) {
      const int t0 = 32 * (k - 1) + 8 * eg;    // block-relative first row (scalar)
      // il2 reads issued early; latency hides under the 38-step v-blur.
      float il2v[8];
#pragma unroll
      for (int p = 0; p < 8; ++p)
        il2v[p] = il2[((t0 + p) & 63) * RPITCH + lane];
      v2f acc2[4];
#pragma unroll
      for (int m = 0; m < 4; ++m) acc2[m] = (v2f){0.f, 0.f};
#pragma unroll
      for (int j = 0; j < 38; ++j) {
        const int row = (t0 - 15 + j + 128) & 63;        // scalar (SALU)
        const float v = hr[row * RPITCH + lane];         // 2-way free
        const v2f vv = {v, v};
#pragma unroll
        for (int m = 0; m < 4; ++m) {
          const int c0 = j - 2 * m;            // compile-time
          if (c0 >= 0 && c0 < 32) {
            const v2f kc = {gc(c0), gc(c0 - 1)};
            acc2[m] = __builtin_elementwise_fma(vv, kc, acc2[m]);
          }
        }
      }
#pragma unroll
      for (int p = 0; p < 8; ++p) {
        const float a = (p & 1) ? acc2[p >> 1].y : acc2[p >> 1].x;
        const size_t ga = base + (size_t)(y0 + t0 + p) * W_ + x0 + lane;
        // expm1(log1p(ins) + blur) == exp2(log2(1+ins) + blur_log2) - 1
        float r = __builtin_amdgcn_exp2f(a + il2v[p]) - 1.f;
        out[ga] = fminf(fmaxf(r, 0.f), 1.f);
      }
    }
  }
}

extern "C" void kernel_launch(void* const* d_in, const int* in_sizes, int n_in,
                              void* d_out, int out_size, void* d_ws, size_t ws_size,
                              hipStream_t stream) {
  const float* bg  = (const float*)d_in[0];
  const float* ins = (const float*)d_in[1];
  float* out = (float*)d_out;
  retinex_roll<<<dim3(8, 2, NIMG), dim3(256), 0, stream>>>(bg, ins, out);
}